// Round 5
// baseline (214.852 us; speedup 1.0000x reference)
//
#include <hip/hip_runtime.h>

// ConvTranspose4d: temporal valid conv (KT=3) of ConvTranspose3d(stride 2, pad 1, k=3).
// Gather form: out[co,f,od,oh,ow] = sum_{i,ci,kd,kh,kw} x[ci,f+i,id,ih,iw] * W[ci,co,i,kd,kh,kw]
//   id=(od+1-kd)/2 valid iff parity matches; all parity-valid taps in range (24->47, 48->95).
// Even coord -> 1 tap (k=1); odd coord -> 2 taps (k=0,2).
// R5: occupancy round. R4 measured VGPR=72 (just past the 64-VGPR cliff -> 4 waves/SIMD)
//     and only 8.4 waves/CU resident. NOW=4 for ALL classes (acc 64->32 VGPR) +
//     __launch_bounds__(192,8) forces <=64 VGPR -> 8 waves/SIMD cap; grid 2106->3384
//     blocks (13.2/CU). Bijective XCD swizzle back (3384%8==0) since 2x blocks double
//     x re-reads; proven time-neutral at worst (R1/R3 A/B).

typedef float f4u __attribute__((ext_vector_type(4), aligned(4)));  // unaligned-ok out vec
typedef float f2a __attribute__((ext_vector_type(2)));              // 8B-aligned

namespace {
constexpr int T_ = 8, D_ = 24, H_ = 48, W_ = 48;
constexpr int TO = 6, DO_ = 47, HO = 95, WO = 95;
constexpr int XCS = T_ * D_ * H_ * W_;
constexpr int XFS = D_ * H_ * W_;
constexpr int XDS = H_ * W_;
constexpr long OCS = (long)TO * DO_ * HO * WO;
constexpr int OFS = DO_ * HO * WO;
constexpr int ODS = HO * WO;

// Segments (work id L): S0 = od odd & oh odd (12 taps), S1 = od odd & oh even (6),
// S2 = od even & oh odd (6), S3 = od even & oh even (3 taps).
constexpr int S0_END = 828, S1_END = 1656, S2_END = 2520, NWG = 3384;  // 3384 % 8 == 0

template<int ND, int NH>
__device__ __forceinline__ void conv_body(
    const float* __restrict__ x, const float* __restrict__ w,
    float* __restrict__ out, int f, int od, int oh, int t)
{
  const int iwb = 2 * t;                  // iw base; t in 0..23, ow = 4t..4t+3
  const int xext = (t < 23) ? 2 : 0;      // clamp: elem feeds only discarded ow=95

  float acc[8][4];
  #pragma unroll
  for (int co = 0; co < 8; ++co)
    #pragma unroll
    for (int m = 0; m < 4; ++m) acc[co][m] = 0.f;

  #pragma unroll 1
  for (int ci = 0; ci < 8; ++ci) {
    // SGPR base; all weight offsets below are compile-time immediates from here.
    const float* pw = w + __builtin_amdgcn_readfirstlane(ci * 648);
    const float* pxc = x + ci * XCS + iwb;
    #pragma unroll
    for (int i = 0; i < 3; ++i) {
      #pragma unroll
      for (int a = 0; a < ND; ++a) {
        const int KD = (ND == 1) ? 1 : (a == 0 ? 0 : 2);
        const int id = (ND == 1) ? (od >> 1) : (a == 0 ? ((od + 1) >> 1) : ((od - 1) >> 1));
        #pragma unroll
        for (int b = 0; b < NH; ++b) {
          const int KH = (NH == 1) ? 1 : (b == 0 ? 0 : 2);
          const int ih = (NH == 1) ? (oh >> 1) : (b == 0 ? ((oh + 1) >> 1) : ((oh - 1) >> 1));
          const int WOFF = i * 27 + KD * 9 + KH * 3;   // compile-time
          const float* px = pxc + (f + i) * XFS + id * XDS + ih * W_;
          const f2a xa = *(const f2a*)px;              // iw = 2t, 2t+1 (8B aligned)
          const float x0 = xa.x, x1 = xa.y;
          const float xb = px[xext];                   // iw = 2t+2
          #pragma unroll
          for (int co = 0; co < 8; ++co) {
            const float w0 = pw[co * 81 + WOFF + 0];
            const float w1 = pw[co * 81 + WOFF + 1];
            const float w2 = pw[co * 81 + WOFF + 2];
            acc[co][0] = fmaf(x0, w1, acc[co][0]);                    // ow=4t   (kw=1)
            acc[co][2] = fmaf(x1, w1, acc[co][2]);                    // ow=4t+2 (kw=1)
            acc[co][1] = fmaf(x1, w0, fmaf(x0, w2, acc[co][1]));      // ow=4t+1 (kw=0,2)
            acc[co][3] = fmaf(xb, w0, fmaf(x1, w2, acc[co][3]));      // ow=4t+3 (kw=0,2)
          }
        }
      }
    }
  }

  const long ob = (long)f * OFS + (long)od * ODS + (long)oh * HO + 4 * t;
  #pragma unroll
  for (int co = 0; co < 8; ++co) {
    float* po = out + co * OCS + ob;
    if (t < 23) {
      f4u v; v.x = acc[co][0]; v.y = acc[co][1]; v.z = acc[co][2]; v.w = acc[co][3];
      *(f4u*)po = v;
    } else {                              // ow = 92..94 (ow=95 doesn't exist)
      po[0] = acc[co][0]; po[1] = acc[co][1]; po[2] = acc[co][2];
    }
  }
}

__global__ __launch_bounds__(192, 8) void convt4d_kernel(
    const float* __restrict__ x, const float* __restrict__ w,
    float* __restrict__ out)
{
  // bijective XCD swizzle: blocks landing on the same XCD get consecutive work ids
  const int L = (blockIdx.x & 7) * (NWG / 8) + (blockIdx.x >> 3);
  const int tid = threadIdx.x;
  const int t = tid % 24;                 // ow group: ow in [4t, 4t+4)
  const int yy = tid / 24;                // 0..7 rows per block

  if (L < S0_END) {                       // od odd, oh odd
    const int ohb = L % 6; const int rest = L / 6;
    const int dd = rest % 23; const int f = rest / 23;
    const int row = ohb * 8 + yy; if (row >= 47) return;
    conv_body<2, 2>(x, w, out, f, 2 * dd + 1, 2 * row + 1, t);
  } else if (L < S1_END) {                // od odd, oh even
    const int b2 = L - S0_END;
    const int ohb = b2 % 6; const int rest = b2 / 6;
    const int dd = rest % 23; const int f = rest / 23;
    const int row = ohb * 8 + yy;         // 0..47, always valid
    conv_body<2, 1>(x, w, out, f, 2 * dd + 1, 2 * row, t);
  } else if (L < S2_END) {                // od even, oh odd
    const int b2 = L - S1_END;
    const int ohb = b2 % 6; const int rest = b2 / 6;
    const int dd = rest % 24; const int f = rest / 24;
    const int row = ohb * 8 + yy; if (row >= 47) return;
    conv_body<1, 2>(x, w, out, f, 2 * dd, 2 * row + 1, t);
  } else {                                // od even, oh even
    const int b2 = L - S2_END;
    const int ohb = b2 % 6; const int rest = b2 / 6;
    const int dd = rest % 24; const int f = rest / 24;
    const int row = ohb * 8 + yy;
    conv_body<1, 1>(x, w, out, f, 2 * dd, 2 * row, t);
  }
}
}  // namespace

extern "C" void kernel_launch(void* const* d_in, const int* in_sizes, int n_in,
                              void* d_out, int out_size, void* d_ws, size_t ws_size,
                              hipStream_t stream) {
  const float* x = (const float*)d_in[0];
  const float* w = (const float*)d_in[1];
  float* out = (float*)d_out;
  hipLaunchKernelGGL(convt4d_kernel, dim3(NWG), dim3(192), 0, stream, x, w, out);
}

// Round 6
// 85.699 us; speedup vs baseline: 2.5071x; 2.5071x over previous
//
#include <hip/hip_runtime.h>

// ConvTranspose4d: temporal valid conv (KT=3) of ConvTranspose3d(stride 2, pad 1, k=3).
// Gather form: out[co,f,od,oh,ow] = sum_{i,ci,kd,kh,kw} x[ci,f+i,id,ih,iw] * W[ci,co,i,kd,kh,kw]
//   id=(od+1-kd)/2 valid iff parity matches; all parity-valid taps in range (24->47, 48->95).
// R6 = R4 (best: 79us) + device-side weight PRE-PACK into d_ws:
//   packed[class][ci][tap][co][3] contiguous -> per-ci weight block is a dense run of
//   compile-time immediates off an SGPR base -> few s_load_dwordx16 bursts + one wait,
//   instead of ~50 scattered narrow s_loads whose lgkmcnt(0) waits serialized the wave
//   (R4 post-mortem: 41us VALU-issue vs 21us FMA floor, 52% busy, nothing saturated).
// R5's NOW=4-everywhere / swizzle / 3384-block config REVERTED (write RMW blowup:
//   WRITE 87->219MB, dur 233us).

typedef float f4u __attribute__((ext_vector_type(4), aligned(4)));  // unaligned-ok out vec
typedef float f4a __attribute__((ext_vector_type(4)));              // 16B-aligned
typedef float f2a __attribute__((ext_vector_type(2)));              // 8B-aligned

namespace {
constexpr int T_ = 8, D_ = 24, H_ = 48, W_ = 48;
constexpr int TO = 6, DO_ = 47, HO = 95, WO = 95;
constexpr int XCS = T_ * D_ * H_ * W_;
constexpr int XFS = D_ * H_ * W_;
constexpr int XDS = H_ * W_;
constexpr long OCS = (long)TO * DO_ * HO * WO;
constexpr int OFS = DO_ * HO * WO;
constexpr int ODS = HO * WO;

// Segments: S0 = od odd & oh odd (12 taps, 4 ow/thr), S1 = od odd & oh even,
// S2 = od even & oh odd, S3 = od even & oh even. Grid = 828+414+432+432 = 2106.
constexpr int S0_END = 828, S1_END = 1242, S2_END = 1674, NWG = 2106;

// packed-weight float offsets per class: [ci][tap][co][3], size 8*NT*24
constexpr int PB0 = 0, PB1 = 2304, PB2 = 3456, PB3 = 4608;  // total 5184 floats

__device__ __forceinline__ void pack_class(
    const float* __restrict__ w, float* __restrict__ p,
    int base, int ND, int NH, int NT, int tid, int nthr)
{
  const int cnt = 8 * NT * 24;
  for (int e = tid; e < cnt; e += nthr) {
    const int kw = e % 3;
    const int co = (e / 3) % 8;
    const int tap = (e / 24) % NT;
    const int ci = e / (24 * NT);
    const int i_ = tap / (ND * NH);
    const int r = tap % (ND * NH);
    const int a = r / NH, b = r % NH;
    const int KD = (ND == 1) ? 1 : (a ? 2 : 0);
    const int KH = (NH == 1) ? 1 : (b ? 2 : 0);
    p[base + e] = w[ci * 648 + co * 81 + i_ * 27 + KD * 9 + KH * 3 + kw];
  }
}

__global__ __launch_bounds__(256) void pack_kernel(
    const float* __restrict__ w, float* __restrict__ p)
{
  const int tid = blockIdx.x * 256 + threadIdx.x;
  const int nthr = gridDim.x * 256;
  pack_class(w, p, PB0, 2, 2, 12, tid, nthr);
  pack_class(w, p, PB1, 2, 1, 6, tid, nthr);
  pack_class(w, p, PB2, 1, 2, 6, tid, nthr);
  pack_class(w, p, PB3, 1, 1, 3, tid, nthr);
}

template<int ND, int NH, int NOW, int PBASE>
__device__ __forceinline__ void conv_body(
    const float* __restrict__ x, const float* __restrict__ wp,
    float* __restrict__ out, int f, int od, int oh, int t)
{
  constexpr int NT = 3 * ND * NH;
  const int iwb = (NOW == 8 ? 4 : 2) * t;
  const int TMAX = (NOW == 8) ? 11 : 23;
  const int xext = (t < TMAX) ? (NOW / 2) : 0;  // clamp: extra elem feeds only discarded ow=95

  float acc[8][NOW];
  #pragma unroll
  for (int co = 0; co < 8; ++co)
    #pragma unroll
    for (int m = 0; m < NOW; ++m) acc[co][m] = 0.f;

  #pragma unroll 1
  for (int ci = 0; ci < 8; ++ci) {
    // dense per-ci weight block: NT*24 consecutive floats; all offsets below are
    // compile-time immediates -> compiler merges into s_load_dwordx16 bursts.
    const float* ps = wp + PBASE + __builtin_amdgcn_readfirstlane(ci * (NT * 24));
    const float* pxc = x + ci * XCS + iwb;
    #pragma unroll
    for (int i = 0; i < 3; ++i) {
      #pragma unroll
      for (int a = 0; a < ND; ++a) {
        const int id = (ND == 1) ? (od >> 1) : (a == 0 ? ((od + 1) >> 1) : ((od - 1) >> 1));
        #pragma unroll
        for (int b = 0; b < NH; ++b) {
          const int ih = (NH == 1) ? (oh >> 1) : (b == 0 ? ((oh + 1) >> 1) : ((oh - 1) >> 1));
          const int TAP = (i * ND + a) * NH + b;       // compile-time
          const int WOFF = TAP * 24;                   // compile-time
          const float* px = pxc + (f + i) * XFS + id * XDS + ih * W_;
          if (NOW == 8) {
            const f4a xa = *(const f4a*)px;            // iw = 4t..4t+3 (16B aligned)
            const float xb = px[xext];                 // iw = 4t+4
            #pragma unroll
            for (int co = 0; co < 8; ++co) {
              const float w0 = ps[WOFF + co * 3 + 0];
              const float w1 = ps[WOFF + co * 3 + 1];
              const float w2 = ps[WOFF + co * 3 + 2];
              acc[co][0] = fmaf(xa.x, w1, acc[co][0]);
              acc[co][2] = fmaf(xa.y, w1, acc[co][2]);
              acc[co][4] = fmaf(xa.z, w1, acc[co][4]);
              acc[co][6] = fmaf(xa.w, w1, acc[co][6]);
              acc[co][1] = fmaf(xa.y, w0, fmaf(xa.x, w2, acc[co][1]));
              acc[co][3] = fmaf(xa.z, w0, fmaf(xa.y, w2, acc[co][3]));
              acc[co][5] = fmaf(xa.w, w0, fmaf(xa.z, w2, acc[co][5]));
              acc[co][7] = fmaf(xb,   w0, fmaf(xa.w, w2, acc[co][7]));
            }
          } else {
            const f2a xa = *(const f2a*)px;            // iw = 2t, 2t+1 (8B aligned)
            const float x0 = xa.x, x1 = xa.y;
            const float xb = px[xext];                 // iw = 2t+2
            #pragma unroll
            for (int co = 0; co < 8; ++co) {
              const float w0 = ps[WOFF + co * 3 + 0];
              const float w1 = ps[WOFF + co * 3 + 1];
              const float w2 = ps[WOFF + co * 3 + 2];
              acc[co][0] = fmaf(x0, w1, acc[co][0]);
              acc[co][2] = fmaf(x1, w1, acc[co][2]);
              acc[co][1] = fmaf(x1, w0, fmaf(x0, w2, acc[co][1]));
              acc[co][3] = fmaf(xb, w0, fmaf(x1, w2, acc[co][3]));
            }
          }
        }
      }
    }
  }

  const long ob = (long)f * OFS + (long)od * ODS + (long)oh * HO + NOW * t;
  #pragma unroll
  for (int co = 0; co < 8; ++co) {
    float* po = out + co * OCS + ob;
    if (NOW == 8) {
      f4u lo; lo.x = acc[co][0]; lo.y = acc[co][1]; lo.z = acc[co][2]; lo.w = acc[co][3];
      *(f4u*)po = lo;
      if (t < 11) {
        f4u hi; hi.x = acc[co][4]; hi.y = acc[co][5]; hi.z = acc[co][6]; hi.w = acc[co][7];
        *(f4u*)(po + 4) = hi;
      } else {                         // ow = 88..94 (ow=95 doesn't exist)
        po[4] = acc[co][4]; po[5] = acc[co][5]; po[6] = acc[co][6];
      }
    } else {
      if (t < 23) {
        f4u v; v.x = acc[co][0]; v.y = acc[co][1]; v.z = acc[co][2]; v.w = acc[co][3];
        *(f4u*)po = v;
      } else {                         // ow = 92..94 (ow=95 doesn't exist)
        po[0] = acc[co][0]; po[1] = acc[co][1]; po[2] = acc[co][2];
      }
    }
  }
}

__global__ __launch_bounds__(192) void convt4d_kernel(
    const float* __restrict__ x, const float* __restrict__ wp,
    float* __restrict__ out)
{
  const int tid = threadIdx.x;
  const int bid = blockIdx.x;
  if (bid < S0_END) {                          // od odd, oh odd: 4 ow/thread
    const int ohb = bid % 6; const int rest = bid / 6;
    const int dd = rest % 23; const int f = rest / 23;
    const int od = 2 * dd + 1;
    const int t = tid % 24, yy = tid / 24;     // 24 ow-groups x 8 rows
    const int row = ohb * 8 + yy; if (row >= 47) return;
    const int oh = 2 * row + 1;
    conv_body<2, 2, 4, PB0>(x, wp, out, f, od, oh, t);
  } else if (bid < S1_END) {                   // od odd, oh even
    const int b2 = bid - S0_END;
    const int ohb = b2 % 3; const int rest = b2 / 3;
    const int dd = rest % 23; const int f = rest / 23;
    const int od = 2 * dd + 1;
    const int t = tid % 12, yy = tid / 12;
    const int oh = 2 * (ohb * 16 + yy);
    conv_body<2, 1, 8, PB1>(x, wp, out, f, od, oh, t);
  } else if (bid < S2_END) {                   // od even, oh odd
    const int b2 = bid - S1_END;
    const int ohb = b2 % 3; const int rest = b2 / 3;
    const int dd = rest % 24; const int f = rest / 24;
    const int od = 2 * dd;
    const int t = tid % 12, yy = tid / 12;
    const int row = ohb * 16 + yy; if (row >= 47) return;
    const int oh = 2 * row + 1;
    conv_body<1, 2, 8, PB2>(x, wp, out, f, od, oh, t);
  } else {                                     // od even, oh even
    const int b2 = bid - S2_END;
    const int ohb = b2 % 3; const int rest = b2 / 3;
    const int dd = rest % 24; const int f = rest / 24;
    const int od = 2 * dd;
    const int t = tid % 12, yy = tid / 12;
    const int oh = 2 * (ohb * 16 + yy);
    conv_body<1, 1, 8, PB3>(x, wp, out, f, od, oh, t);
  }
}
}  // namespace

extern "C" void kernel_launch(void* const* d_in, const int* in_sizes, int n_in,
                              void* d_out, int out_size, void* d_ws, size_t ws_size,
                              hipStream_t stream) {
  const float* x = (const float*)d_in[0];
  const float* w = (const float*)d_in[1];
  float* out = (float*)d_out;
  float* wp = (float*)d_ws;                    // 5184 floats = 20.7 KB scratch
  hipLaunchKernelGGL(pack_kernel, dim3(8), dim3(256), 0, stream, w, wp);
  hipLaunchKernelGGL(convt4d_kernel, dim3(NWG), dim3(192), 0, stream, x, wp, out);
}